// Round 8
// baseline (666.201 us; speedup 1.0000x reference)
//
#include <hip/hip_runtime.h>
#include <hip/hip_cooperative_groups.h>

// FloodPath R11: fused cooperative pack+flood (one kernel, one dispatch).
//   Grid = 2048 blocks (exactly 8/CU co-resident: LDS 19.5KB, VGPR<=64 via
//   __launch_bounds__(256,8)). Block nl packs rows {2nl, 2nl+1} — which lie
//   inside the SAME band (nl>>4) it floods — so packed planes are written and
//   re-read by the same XCD's L2, regardless of dispatch mapping. Grid-wide
//   sync via cooperative_groups::this_grid().sync() between phases.
//   Kept from R10 (354-best lineage): wave 64x64 register window, 16 shfl
//   dilation steps, bit-sliced counters, cross-wave plane transpose, packed
//   dwordx4 NT output stores (197MB ideal), NT loads for read-once streams,
//   fc prefetch hoisted above dilation.
//   Fallback: if hipLaunchCooperativeKernel fails (e.g. capture), launch
//   R10's two-kernel path — neutral, not broken.

namespace cg = cooperative_groups;

typedef unsigned long long u64;
typedef float f32x4 __attribute__((ext_vector_type(4)));
typedef float f32x2 __attribute__((ext_vector_type(2)));

#define HH 4096
#define WW 4096
#define WPR 64            // u64 words per image row
#define NSTEPS 16
#define HALO 16
#define IT 32             // interior tile side per wave (64x64 window)

// ---------------- shared flood-tile body ----------------
__device__ __forceinline__ void flood_tile(
    const u64* __restrict__ occP, const u64* __restrict__ flP,
    const float* __restrict__ flood_count, float* __restrict__ out,
    u64* __restrict__ planeBuf /*[4*IT*7]*/, float* __restrict__ out2Buf /*[4*768]*/,
    int tile_r0, int bc0, int lane, int wv)
{
    const int tile_c0 = bc0 + wv * IT;

    // ---- Stage window: rows tile_r0-16+lane, cols tile_c0-16 .. +47.
    const int gr  = tile_r0 - HALO + lane;
    const bool rin = (gr >= 0) & (gr < HH);
    const int s   = tile_c0 - HALO;
    const int q0  = ((s + 64) >> 6) - 1;         // floor(s/64), s >= -64
    const int sh  = s - (q0 << 6);

    const size_t base = (size_t)(rin ? gr : 0) * WPR;
    const int qa = min(max(q0, 0), WPR - 1);
    const int qb = min(max(q0 + 1, 0), WPR - 1);
    u64 o0 = occP[base + qa], o1 = occP[base + qb];
    u64 f0 = flP [base + qa], f1 = flP [base + qb];
    const bool va = rin & (q0 >= 0);
    const bool vb = rin & (q0 + 1 < WPR);
    if (!va) { o0 = ~0ull; f0 = 0ull; }          // OOB => wall, no flood
    if (!vb) { o1 = ~0ull; f1 = 0ull; }
    const u64 occ = (o0 >> sh) | (sh ? (o1 << (64 - sh)) : 0ull);
    u64       f   = (f0 >> sh) | (sh ? (f1 << (64 - sh)) : 0ull);

    // ---- fc prefetch for output iteration 0 (hides under dilation VALU).
    const int half = lane >> 5;
    const int l32  = lane & 31;
    const int col0 = l32 * 4;
    const float* fcbase = flood_count +
        (size_t)(tile_r0 + wv * 8 + half) * WW + bc0 + col0;
    f32x4 fc_next = __builtin_nontemporal_load((const f32x4*)fcbase);

    // ---- 16 dilation steps, fully in registers.
    const u64 nocc = ~occ;
    u64 c0 = 0, c1 = 0, c2 = 0, c3 = 0, c4 = 0;
#pragma unroll
    for (int it = 0; it < NSTEPS; ++it) {
        u64 up = __shfl_up(f, 1);
        u64 dn = __shfl_down(f, 1);
        if (lane == 0)  up = 0ull;
        if (lane == 63) dn = 0ull;
        f = nocc & (f | (f << 1) | (f >> 1) | up | dn);
        u64 c = f, t;
        t = c0; c0 = t ^ c; c = t & c;
        t = c1; c1 = t ^ c; c = t & c;
        t = c2; c2 = t ^ c; c = t & c;
        t = c3; c3 = t ^ c; c = t & c;
        c4 ^= c;                                 // max 16: no carry out
    }

    // ---- Cross-wave transpose: lanes 16..47 hold interior rows.
    if (lane >= HALO && lane < HALO + IT) {
        u64* p = planeBuf + ((size_t)wv * IT + (lane - HALO)) * 7;
        p[0] = occ; p[1] = f;
        p[2] = c0; p[3] = c1; p[4] = c2; p[5] = c3; p[6] = c4;
    }
    __syncthreads();

    // ---- Output: wave wv owns interior rows wv*8..wv*8+7, full 128-col
    //      width, as 4 row-pairs.
    const int sw   = col0 >> 5;                  // source wave for my 4 px
    const int bit0 = HALO + (col0 & 31);
    float* out2w = out2Buf + wv * 768;
    for (int t = 0; t < 4; ++t) {
        const f32x4 fc4 = fc_next;
        if (t + 1 < 4)
            fc_next = __builtin_nontemporal_load(
                (const f32x4*)(fcbase + (size_t)(t + 1) * 2 * WW));

        const int rA   = wv * 8 + 2 * t;
        const int irow = rA + half;
        const u64* p = planeBuf + ((size_t)sw * IT + irow) * 7;
        const u64 ow = p[0], fw = p[1];
        const u64 k0 = p[2], k1 = p[3], k2 = p[4], k3 = p[5], k4 = p[6];

        float v[12];
#pragma unroll
        for (int j = 0; j < 4; ++j) {
            const int bit = bit0 + j;
            int cv = (int)((k0 >> bit) & 1ull)
                   + ((int)((k1 >> bit) & 1ull) << 1)
                   + ((int)((k2 >> bit) & 1ull) << 2)
                   + ((int)((k3 >> bit) & 1ull) << 3)
                   + ((int)((k4 >> bit) & 1ull) << 4);
            v[j*3+0] = (float)((ow >> bit) & 1ull);
            v[j*3+1] = (float)((fw >> bit) & 1ull);
            v[j*3+2] = (float)cv + fc4[j];
        }
        float* dst = out2w + half * 384 + l32 * 12;
        *(f32x4*)(dst + 0) = (f32x4){v[0], v[1], v[2],  v[3]};
        *(f32x4*)(dst + 4) = (f32x4){v[4], v[5], v[6],  v[7]};
        *(f32x4*)(dst + 8) = (f32x4){v[8], v[9], v[10], v[11]};

        __syncthreads();

#pragma unroll
        for (int st = 0; st < 3; ++st) {
            const int L   = st * 256 + lane * 4;
            const int row = (L >= 384) ? 1 : 0;
            const int off = L - row * 384;
            const f32x4 q = *(const f32x4*)(out2w + L);
            __builtin_nontemporal_store(q,
                (f32x4*)(out + ((size_t)(tile_r0 + rA + row) * WW + bc0) * 3
                         + off));
        }
    }
}

// ---------------- fused cooperative kernel ----------------
__global__ __launch_bounds__(256, 8) void fused_kernel(
    const float* __restrict__ flood_input,
    const float* __restrict__ flood_count,
    u64* __restrict__ occP, u64* __restrict__ flP,
    float* __restrict__ out)
{
    __shared__ u64   plane[4 * IT * 7];          // 7168 B
    __shared__ float out2 [4 * 768];             // 12288 B

    const int tid  = threadIdx.x;
    const int lane = tid & 63;
    const int wv   = tid >> 6;

    const int wgid = blockIdx.x;                     // 0..2047
    const int nl   = (wgid & 7) * 256 + (wgid >> 3); // XCD chunk swizzle

    // ---- Phase 1: pack rows {2nl, 2nl+1} (inside this block's flood band).
    {
        const int prow  = 2 * nl + (wv >> 1);
        const int wbase = (wv & 1) * 32;
        const float* rp = flood_input + (size_t)prow * WW * 2;
#pragma unroll
        for (int b = 0; b < 8; ++b) {
            float vx[4], vy[4];
#pragma unroll
            for (int j = 0; j < 4; ++j) {
                const int w = wbase + b * 4 + j;
                const f32x2 v = __builtin_nontemporal_load(
                    (const f32x2*)(rp + ((w << 6) + lane) * 2));
                vx[j] = v[0]; vy[j] = v[1];
            }
#pragma unroll
            for (int j = 0; j < 4; ++j) {
                const int w = wbase + b * 4 + j;
                const u64 om = __ballot(vx[j] > 0.5f);
                const u64 fm = __ballot(vy[j] > 0.5f);
                if (lane == 0) {
                    occP[(size_t)prow * WPR + w] = om;
                    flP [(size_t)prow * WPR + w] = fm;
                }
            }
        }
    }

    cg::this_grid().sync();

    // ---- Phase 2: two flood tiles (band nl>>4, cols (2nl&31), (2nl&31)+1).
    const int by  = nl >> 4;
    const int bx0 = (2 * nl) & 31;               // even; bx0+1 same band
    const int tile_r0 = by * IT;
#pragma unroll 1
    for (int tt = 0; tt < 2; ++tt) {
        const int bc0 = (bx0 + tt) * (4 * IT);
        flood_tile(occP, flP, flood_count, out, plane, out2,
                   tile_r0, bc0, lane, wv);
    }
}

// ---------------- fallback: R10 two-kernel path ----------------
__global__ __launch_bounds__(256) void pack_kernel(
    const float* __restrict__ flood_input,
    u64* __restrict__ occP, u64* __restrict__ flP)
{
    const int lane = threadIdx.x & 63;
    const int wv   = threadIdx.x >> 6;
    const int r    = blockIdx.x;
#pragma unroll
    for (int b = 0; b < 2; ++b) {
        float vx[8], vy[8];
#pragma unroll
        for (int j = 0; j < 8; ++j) {
            const int w = wv * 16 + b * 8 + j;
            const f32x2 v = __builtin_nontemporal_load(
                (const f32x2*)(flood_input +
                                ((size_t)r * WW + (w << 6) + lane) * 2));
            vx[j] = v[0]; vy[j] = v[1];
        }
#pragma unroll
        for (int j = 0; j < 8; ++j) {
            const int w = wv * 16 + b * 8 + j;
            const u64 om = __ballot(vx[j] > 0.5f);
            const u64 fm = __ballot(vy[j] > 0.5f);
            if (lane == 0) {
                occP[(size_t)r * WPR + w] = om;
                flP [(size_t)r * WPR + w] = fm;
            }
        }
    }
}

__global__ __launch_bounds__(256, 8) void flood_kernel(
    const u64* __restrict__ occP, const u64* __restrict__ flP,
    const float* __restrict__ flood_count,
    float* __restrict__ out)
{
    __shared__ u64   plane[4 * IT * 7];
    __shared__ float out2 [4 * 768];

    const int lane = threadIdx.x & 63;
    const int wv   = threadIdx.x >> 6;

    const int wgid = blockIdx.y * 32 + blockIdx.x;   // 0..4095
    const int nl   = (wgid & 7) * 512 + (wgid >> 3); // XCD chunk swizzle
    const int bx   = nl & 31;
    const int by   = nl >> 5;

    flood_tile(occP, flP, flood_count, out, plane, out2,
               by * IT, bx * (4 * IT), lane, wv);
}

extern "C" void kernel_launch(void* const* d_in, const int* in_sizes, int n_in,
                              void* d_out, int out_size, void* d_ws, size_t ws_size,
                              hipStream_t stream) {
    const float* flood_input = (const float*)d_in[0];  // [4096][4096][2]
    const float* flood_cnt   = (const float*)d_in[1];  // [4096][4096]
    float* out = (float*)d_out;                        // [4096][4096][3]

    u64* occP = (u64*)d_ws;                            // 2 MiB
    u64* flP  = occP + (size_t)HH * WPR;               // 2 MiB

    void* args[] = { (void*)&flood_input, (void*)&flood_cnt,
                     (void*)&occP, (void*)&flP, (void*)&out };
    const hipError_t e = hipLaunchCooperativeKernel(
        (void*)fused_kernel, dim3(2048), dim3(256), args, 0, stream);

    if (e != hipSuccess) {
        // R10 fallback (proven 357.7): two launches, same math.
        pack_kernel<<<dim3(HH), dim3(256), 0, stream>>>(flood_input, occP, flP);
        dim3 grid(WW / (4 * IT), HH / IT);             // 32 x 128
        flood_kernel<<<grid, dim3(256), 0, stream>>>(occP, flP, flood_cnt, out);
    }
}

// Round 9
// 358.689 us; speedup vs baseline: 1.8573x; 1.8573x over previous
//
#include <hip/hip_runtime.h>

// FloodPath R12: R10 minus nontemporal STORES (NT-store write-inflation test).
//   Evidence: R11's fused kernel showed WRITE_SIZE=312MB with packed f32x4 NT
//   stores — same inflation as R4's float3 scatter (315MB) — while R5 (plain
//   packed stores) was the best total. Hypothesis: `nt` on gfx950 bypasses L2
//   write-combining and degrades the 12B/px stream to partial-sector
//   writebacks (~+110MB). R12 keeps R10's proven grafts:
//   (1) bijective XCD band swizzle (plane working set ~560KB/XCD L2),
//   (2) NT LOADS for read-once streams (fc, pack input),
//   (3) fc loads software-pipelined one iteration ahead,
//   and reverts only the out stores to plain f32x4 (write-combined via L2).
//   Cooperative fusion (R11) abandoned: grid.sync() flushes/invalidates the
//   per-XCD L2s (release/acquire), destroying the locality it was meant to
//   create — 407us, latency-bound at 16% HBM.

typedef unsigned long long u64;
typedef float f32x4 __attribute__((ext_vector_type(4)));
typedef float f32x2 __attribute__((ext_vector_type(2)));

#define HH 4096
#define WW 4096
#define WPR 64            // u64 words per image row
#define NSTEPS 16
#define HALO 16
#define IT 32             // interior tile side per wave (64x64 window)

// ---------------- Kernel 1: bitpack ----------------
__global__ __launch_bounds__(256) void pack_kernel(
    const float* __restrict__ flood_input,
    u64* __restrict__ occP, u64* __restrict__ flP)
{
    const int lane = threadIdx.x & 63;
    const int wv   = threadIdx.x >> 6;
    const int r    = blockIdx.x;                  // one image row per block
#pragma unroll
    for (int b = 0; b < 2; ++b) {
        float vx[8], vy[8];
#pragma unroll
        for (int j = 0; j < 8; ++j) {
            const int w = wv * 16 + b * 8 + j;
            const f32x2 v = __builtin_nontemporal_load(
                (const f32x2*)(flood_input +
                                ((size_t)r * WW + (w << 6) + lane) * 2));
            vx[j] = v[0]; vy[j] = v[1];
        }
#pragma unroll
        for (int j = 0; j < 8; ++j) {
            const int w = wv * 16 + b * 8 + j;
            const u64 om = __ballot(vx[j] > 0.5f);
            const u64 fm = __ballot(vy[j] > 0.5f);
            if (lane == 0) {
                occP[(size_t)r * WPR + w] = om;
                flP [(size_t)r * WPR + w] = fm;
            }
        }
    }
}

// ---------------- Kernel 2: flood + count + output ----------------
__global__ __launch_bounds__(256, 8) void flood_kernel(
    const u64* __restrict__ occP, const u64* __restrict__ flP,
    const float* __restrict__ flood_count,
    float* __restrict__ out)
{
    // cross-wave transpose planes: [wave][interior row][occ,f,c0..4] — 7168 B
    __shared__ u64 plane[4][IT][7];
    // per-wave packed output staging: 2 rows x 128 px x 3 ch — 12288 B
    __shared__ float out2[4][2 * 128 * 3];

    const int tid  = threadIdx.x;
    const int lane = tid & 63;
    const int wv   = tid >> 6;

    // ---- Bijective XCD band swizzle (4096 blocks, gridDim = 32 x 128).
    const int wgid = blockIdx.y * 32 + blockIdx.x;   // 0..4095
    const int nl   = (wgid & 7) * 512 + (wgid >> 3); // chunk per XCD
    const int bx   = nl & 31;
    const int by   = nl >> 5;

    const int tile_r0 = by * IT;                     // 0..4064
    const int tile_c0 = bx * (4 * IT) + wv * IT;     // wave's 32 cols
    const int bc0     = bx * (4 * IT);               // block col start

    // ---- Stage window: rows tile_r0-16+lane, cols tile_c0-16 .. +47.
    const int gr  = tile_r0 - HALO + lane;
    const bool rin = (gr >= 0) & (gr < HH);
    const int s   = tile_c0 - HALO;              // >= -16
    const int q0  = ((s + 64) >> 6) - 1;         // floor(s/64)
    const int sh  = s - (q0 << 6);               // 16 or 48

    const size_t base = (size_t)(rin ? gr : 0) * WPR;
    const int qa = min(max(q0, 0), WPR - 1);
    const int qb = min(max(q0 + 1, 0), WPR - 1);
    u64 o0 = occP[base + qa], o1 = occP[base + qb];
    u64 f0 = flP [base + qa], f1 = flP [base + qb];
    const bool va = rin & (q0 >= 0);
    const bool vb = rin & (q0 + 1 < WPR);
    if (!va) { o0 = ~0ull; f0 = 0ull; }          // OOB => wall, no flood
    if (!vb) { o1 = ~0ull; f1 = 0ull; }
    const u64 occ = (o0 >> sh) | (sh ? (o1 << (64 - sh)) : 0ull);
    u64       f   = (f0 >> sh) | (sh ? (f1 << (64 - sh)) : 0ull);

    // ---- fc prefetch for output iteration 0 (hides under dilation VALU).
    const int half = lane >> 5;                  // 0 or 1: row within pair
    const int l32  = lane & 31;
    const int col0 = l32 * 4;                    // block-local col of 4 px
    const float* fcbase = flood_count +
        (size_t)(tile_r0 + wv * 8 + half) * WW + bc0 + col0;
    f32x4 fc_next = __builtin_nontemporal_load((const f32x4*)fcbase);

    // ---- 16 dilation steps, fully in registers. No barriers.
    const u64 nocc = ~occ;
    u64 c0 = 0, c1 = 0, c2 = 0, c3 = 0, c4 = 0;
#pragma unroll
    for (int it = 0; it < NSTEPS; ++it) {
        u64 up = __shfl_up(f, 1);
        u64 dn = __shfl_down(f, 1);
        if (lane == 0)  up = 0ull;
        if (lane == 63) dn = 0ull;
        f = nocc & (f | (f << 1) | (f >> 1) | up | dn);
        u64 c = f, t;
        t = c0; c0 = t ^ c; c = t & c;
        t = c1; c1 = t ^ c; c = t & c;
        t = c2; c2 = t ^ c; c = t & c;
        t = c3; c3 = t ^ c; c = t & c;
        c4 ^= c;                                 // max 16: no carry out
    }

    // ---- Cross-wave transpose: lanes 16..47 hold interior rows.
    if (lane >= HALO && lane < HALO + IT) {
        u64* p = plane[wv][lane - HALO];
        p[0] = occ; p[1] = f;
        p[2] = c0; p[3] = c1; p[4] = c2; p[5] = c3; p[6] = c4;
    }
    __syncthreads();

    // ---- Output: wave wv owns interior rows wv*8..wv*8+7, full 128-col
    //      width, as 4 row-pairs (exact R5 structure, barriers kept).
    const int sw   = col0 >> 5;                  // source wave for my 4 px
    const int bit0 = HALO + (col0 & 31);
    for (int t = 0; t < 4; ++t) {
        const f32x4 fc4 = fc_next;
        if (t + 1 < 4)
            fc_next = __builtin_nontemporal_load(
                (const f32x4*)(fcbase + (size_t)(t + 1) * 2 * WW));

        const int rA   = wv * 8 + 2 * t;         // pair's first interior row
        const int irow = rA + half;              // this lane's interior row
        const u64* p = plane[sw][irow];
        const u64 ow = p[0], fw = p[1];
        const u64 k0 = p[2], k1 = p[3], k2 = p[4], k3 = p[5], k4 = p[6];

        float v[12];
#pragma unroll
        for (int j = 0; j < 4; ++j) {
            const int bit = bit0 + j;
            int cv = (int)((k0 >> bit) & 1ull)
                   + ((int)((k1 >> bit) & 1ull) << 1)
                   + ((int)((k2 >> bit) & 1ull) << 2)
                   + ((int)((k3 >> bit) & 1ull) << 3)
                   + ((int)((k4 >> bit) & 1ull) << 4);
            v[j*3+0] = (float)((ow >> bit) & 1ull);
            v[j*3+1] = (float)((fw >> bit) & 1ull);
            v[j*3+2] = (float)cv + fc4[j];
        }
        // stage: byte offset = half*1536 + l32*48 (16B aligned, lane-linear)
        float* dst = &out2[wv][half * 384 + l32 * 12];
        *(f32x4*)(dst + 0) = (f32x4){v[0], v[1], v[2],  v[3]};
        *(f32x4*)(dst + 4) = (f32x4){v[4], v[5], v[6],  v[7]};
        *(f32x4*)(dst + 8) = (f32x4){v[8], v[9], v[10], v[11]};

        __syncthreads();   // lockstep store phase (R5-proven)

        // read back linearly, 3 packed PLAIN dwordx4 stores per lane
        //   (NT removed: let L2 write-combine the 12B/px stream)
#pragma unroll
        for (int st = 0; st < 3; ++st) {
            const int L   = st * 256 + lane * 4;   // float idx in 768-float pair
            const int row = (L >= 384) ? 1 : 0;
            const int off = L - row * 384;
            const f32x4 q = *(const f32x4*)(&out2[wv][L]);
            *(f32x4*)(out + ((size_t)(tile_r0 + rA + row) * WW + bc0) * 3
                      + off) = q;
        }
    }
}

extern "C" void kernel_launch(void* const* d_in, const int* in_sizes, int n_in,
                              void* d_out, int out_size, void* d_ws, size_t ws_size,
                              hipStream_t stream) {
    const float* flood_input = (const float*)d_in[0];  // [4096][4096][2]
    const float* flood_cnt   = (const float*)d_in[1];  // [4096][4096]
    float* out = (float*)d_out;                        // [4096][4096][3]

    u64* occP = (u64*)d_ws;                            // 2 MiB
    u64* flP  = occP + (size_t)HH * WPR;               // 2 MiB

    pack_kernel<<<dim3(HH), dim3(256), 0, stream>>>(flood_input, occP, flP);

    dim3 grid(WW / (4 * IT), HH / IT);                 // 32 x 128 = 4096 blocks
    flood_kernel<<<grid, dim3(256), 0, stream>>>(occP, flP, flood_cnt, out);
}

// Round 10
// 345.535 us; speedup vs baseline: 1.9280x; 1.0381x over previous
//
#include <hip/hip_runtime.h>

// FloodPath R13: transposed (word-major) plane layout — staging gather fix.
//   Evidence: 9 variants pinned controllable cost at 109-115us vs ~65us
//   stream floor; R4 counters (HBM 40%, VALU 19%, occ 66%) = latency-bound.
//   The one structure common to ALL variants: row-major planes make each of
//   flood's 4 staging loads a 64-row stride-512B gather = 64 cache lines per
//   instruction. R13 stores planes occT[word][row] so the same load is one
//   contiguous 512B segment (8 lines). Pack writes transposed via a
//   wave-private LDS column buffer (coalesced 512B column stores).
//   Kept from R12 (best-tied): XCD band swizzle, NT loads for read-once
//   streams, fc prefetch one iteration ahead, plain packed dwordx4 stores,
//   cross-wave plane transpose + lockstep store phase.

typedef unsigned long long u64;
typedef float f32x4 __attribute__((ext_vector_type(4)));
typedef float f32x2 __attribute__((ext_vector_type(2)));

#define HH 4096
#define WW 4096
#define WPR 64            // u64 words per image row
#define NSTEPS 16
#define HALO 16
#define IT 32             // interior tile side per wave (64x64 window)

// ---------------- Kernel 1: bitpack (transposed output) ----------------
//   Block = 64 rows x 4 word-columns (one per wave). Grid = 64*16 = 1024.
//   Wave wv: for r in 0..63 load row (r0+r), word w; ballot; lane0 -> LDS.
//   Then one contiguous 512B column store per plane: occT[w][r0+lane].
__global__ __launch_bounds__(256) void pack_kernel(
    const float* __restrict__ flood_input,
    u64* __restrict__ occT, u64* __restrict__ flT)
{
    __shared__ u64 lb[2][4][64];                 // [plane][wave][row] 4 KiB

    const int lane = threadIdx.x & 63;
    const int wv   = threadIdx.x >> 6;
    const int r0   = (blockIdx.x >> 4) * 64;     // row group
    const int w    = (blockIdx.x & 15) * 4 + wv; // word column 0..63

    const float* src = flood_input +
        ((size_t)r0 * WW + (w << 6) + lane) * 2;
#pragma unroll 4
    for (int rb = 0; rb < 64; rb += 8) {
        float vx[8], vy[8];
#pragma unroll
        for (int j = 0; j < 8; ++j) {
            const f32x2 v = __builtin_nontemporal_load(
                (const f32x2*)(src + (size_t)(rb + j) * (WW * 2)));
            vx[j] = v[0]; vy[j] = v[1];
        }
#pragma unroll
        for (int j = 0; j < 8; ++j) {
            const u64 om = __ballot(vx[j] > 0.5f);
            const u64 fm = __ballot(vy[j] > 0.5f);
            if (lane == 0) {
                lb[0][wv][rb + j] = om;
                lb[1][wv][rb + j] = fm;
            }
        }
    }
    // lb[*][wv][*] is wave-private (written and read by wave wv only).
    asm volatile("s_waitcnt lgkmcnt(0)" ::: "memory");
    occT[(size_t)w * HH + r0 + lane] = lb[0][wv][lane];
    flT [(size_t)w * HH + r0 + lane] = lb[1][wv][lane];
}

// ---------------- Kernel 2: flood + count + output ----------------
__global__ __launch_bounds__(256, 8) void flood_kernel(
    const u64* __restrict__ occT, const u64* __restrict__ flT,
    const float* __restrict__ flood_count,
    float* __restrict__ out)
{
    // cross-wave transpose planes: [wave][interior row][occ,f,c0..4] — 7168 B
    __shared__ u64 plane[4][IT][7];
    // per-wave packed output staging: 2 rows x 128 px x 3 ch — 12288 B
    __shared__ float out2[4][2 * 128 * 3];

    const int tid  = threadIdx.x;
    const int lane = tid & 63;
    const int wv   = tid >> 6;

    // ---- Bijective XCD band swizzle (4096 blocks, gridDim = 32 x 128).
    const int wgid = blockIdx.y * 32 + blockIdx.x;   // 0..4095
    const int nl   = (wgid & 7) * 512 + (wgid >> 3); // chunk per XCD
    const int bx   = nl & 31;
    const int by   = nl >> 5;

    const int tile_r0 = by * IT;                     // 0..4064
    const int tile_c0 = bx * (4 * IT) + wv * IT;     // wave's 32 cols
    const int bc0     = bx * (4 * IT);               // block col start

    // ---- Stage window from TRANSPOSED planes: contiguous 512B per load.
    const int gr   = tile_r0 - HALO + lane;
    const bool rin = (gr >= 0) & (gr < HH);
    const int grc  = min(max(gr, 0), HH - 1);
    const int s    = tile_c0 - HALO;             // >= -16
    const int q0   = ((s + 64) >> 6) - 1;        // floor(s/64)
    const int sh   = s - (q0 << 6);              // 16 or 48

    const bool va = rin & (q0 >= 0);
    const bool vb = rin & (q0 + 1 < WPR);
    const int qa = max(q0, 0);
    const int qb = min(q0 + 1, WPR - 1);
    u64 o0 = occT[(size_t)qa * HH + grc], o1 = occT[(size_t)qb * HH + grc];
    u64 f0 = flT [(size_t)qa * HH + grc], f1 = flT [(size_t)qb * HH + grc];
    if (!va) { o0 = ~0ull; f0 = 0ull; }          // OOB => wall, no flood
    if (!vb) { o1 = ~0ull; f1 = 0ull; }
    const u64 occ = (o0 >> sh) | (sh ? (o1 << (64 - sh)) : 0ull);
    u64       f   = (f0 >> sh) | (sh ? (f1 << (64 - sh)) : 0ull);

    // ---- fc prefetch for output iteration 0 (hides under dilation VALU).
    const int half = lane >> 5;                  // 0 or 1: row within pair
    const int l32  = lane & 31;
    const int col0 = l32 * 4;                    // block-local col of 4 px
    const float* fcbase = flood_count +
        (size_t)(tile_r0 + wv * 8 + half) * WW + bc0 + col0;
    f32x4 fc_next = __builtin_nontemporal_load((const f32x4*)fcbase);

    // ---- 16 dilation steps, fully in registers. No barriers.
    const u64 nocc = ~occ;
    u64 c0 = 0, c1 = 0, c2 = 0, c3 = 0, c4 = 0;
#pragma unroll
    for (int it = 0; it < NSTEPS; ++it) {
        u64 up = __shfl_up(f, 1);
        u64 dn = __shfl_down(f, 1);
        if (lane == 0)  up = 0ull;
        if (lane == 63) dn = 0ull;
        f = nocc & (f | (f << 1) | (f >> 1) | up | dn);
        u64 c = f, t;
        t = c0; c0 = t ^ c; c = t & c;
        t = c1; c1 = t ^ c; c = t & c;
        t = c2; c2 = t ^ c; c = t & c;
        t = c3; c3 = t ^ c; c = t & c;
        c4 ^= c;                                 // max 16: no carry out
    }

    // ---- Cross-wave transpose: lanes 16..47 hold interior rows.
    if (lane >= HALO && lane < HALO + IT) {
        u64* p = plane[wv][lane - HALO];
        p[0] = occ; p[1] = f;
        p[2] = c0; p[3] = c1; p[4] = c2; p[5] = c3; p[6] = c4;
    }
    __syncthreads();

    // ---- Output: wave wv owns interior rows wv*8..wv*8+7, full 128-col
    //      width, as 4 row-pairs.
    const int sw   = col0 >> 5;                  // source wave for my 4 px
    const int bit0 = HALO + (col0 & 31);
    for (int t = 0; t < 4; ++t) {
        const f32x4 fc4 = fc_next;
        if (t + 1 < 4)
            fc_next = __builtin_nontemporal_load(
                (const f32x4*)(fcbase + (size_t)(t + 1) * 2 * WW));

        const int rA   = wv * 8 + 2 * t;         // pair's first interior row
        const int irow = rA + half;              // this lane's interior row
        const u64* p = plane[sw][irow];
        const u64 ow = p[0], fw = p[1];
        const u64 k0 = p[2], k1 = p[3], k2 = p[4], k3 = p[5], k4 = p[6];

        float v[12];
#pragma unroll
        for (int j = 0; j < 4; ++j) {
            const int bit = bit0 + j;
            int cv = (int)((k0 >> bit) & 1ull)
                   + ((int)((k1 >> bit) & 1ull) << 1)
                   + ((int)((k2 >> bit) & 1ull) << 2)
                   + ((int)((k3 >> bit) & 1ull) << 3)
                   + ((int)((k4 >> bit) & 1ull) << 4);
            v[j*3+0] = (float)((ow >> bit) & 1ull);
            v[j*3+1] = (float)((fw >> bit) & 1ull);
            v[j*3+2] = (float)cv + fc4[j];
        }
        // stage: byte offset = half*1536 + l32*48 (16B aligned, lane-linear)
        float* dst = &out2[wv][half * 384 + l32 * 12];
        *(f32x4*)(dst + 0) = (f32x4){v[0], v[1], v[2],  v[3]};
        *(f32x4*)(dst + 4) = (f32x4){v[4], v[5], v[6],  v[7]};
        *(f32x4*)(dst + 8) = (f32x4){v[8], v[9], v[10], v[11]};

        __syncthreads();   // lockstep store phase

        // read back linearly, 3 packed plain dwordx4 stores per lane
#pragma unroll
        for (int st = 0; st < 3; ++st) {
            const int L   = st * 256 + lane * 4;   // float idx in 768-float pair
            const int row = (L >= 384) ? 1 : 0;
            const int off = L - row * 384;
            const f32x4 q = *(const f32x4*)(&out2[wv][L]);
            *(f32x4*)(out + ((size_t)(tile_r0 + rA + row) * WW + bc0) * 3
                      + off) = q;
        }
    }
}

extern "C" void kernel_launch(void* const* d_in, const int* in_sizes, int n_in,
                              void* d_out, int out_size, void* d_ws, size_t ws_size,
                              hipStream_t stream) {
    const float* flood_input = (const float*)d_in[0];  // [4096][4096][2]
    const float* flood_cnt   = (const float*)d_in[1];  // [4096][4096]
    float* out = (float*)d_out;                        // [4096][4096][3]

    u64* occT = (u64*)d_ws;                            // 2 MiB, [word][row]
    u64* flT  = occT + (size_t)WPR * HH;               // 2 MiB, [word][row]

    pack_kernel<<<dim3(64 * 16), dim3(256), 0, stream>>>(flood_input, occT, flT);

    dim3 grid(WW / (4 * IT), HH / IT);                 // 32 x 128 = 4096 blocks
    flood_kernel<<<grid, dim3(256), 0, stream>>>(occT, flT, flood_cnt, out);
}